// Round 12
// baseline (369.754 us; speedup 1.0000x reference)
//
#include <hip/hip_runtime.h>
#include <math.h>

#define N1 20000
#define NE 320000
#define CIN 256
#define C1 512
#define C2 256
#define K1 10000
#define K2 5000
#define NOUT 128
#define EPSV 1e-5f
#define CM_ROWS 128
#define KPT 20

typedef __attribute__((ext_vector_type(8))) short bf16x8;
typedef __attribute__((ext_vector_type(4))) float f32x4;

static inline unsigned cdiv(unsigned a, unsigned b) { return (a + b - 1) / b; }

__device__ inline ushort f2bf(float f) {
    unsigned u = __float_as_uint(f);
    unsigned r = u + 0x7FFFu + ((u >> 16) & 1u);
    return (ushort)(r >> 16);
}
__device__ inline float bf2f(ushort u) { return __uint_as_float(((unsigned)u) << 16); }

// block-cooperative fold of {sum,sumsq} partials -> mean/istd (256-thread blocks).
// Deterministic: fixed order per block, identical across blocks.
__device__ void block_stats(const float* __restrict__ Sp, int nb, float inv_cnt,
                            float& mean, float& istd) {
    __shared__ float bs_ls[256], bs_lq[256];
    float s = 0.f, q = 0.f;
    for (int i = threadIdx.x; i < nb; i += 256) { s += Sp[2 * i]; q += Sp[2 * i + 1]; }
    bs_ls[threadIdx.x] = s; bs_lq[threadIdx.x] = q;
    __syncthreads();
    for (int off = 128; off > 0; off >>= 1) {
        if ((int)threadIdx.x < off) {
            bs_ls[threadIdx.x] += bs_ls[threadIdx.x + off];
            bs_lq[threadIdx.x] += bs_lq[threadIdx.x + off];
        }
        __syncthreads();
    }
    mean = bs_ls[0] * inv_cnt;
    float var = bs_lq[0] * inv_cnt - mean * mean;
    istd = 1.f / (sqrtf(fmaxf(var, 0.f)) + EPSV);
}

// ---------------- f32 -> bf16 (+ zero an int buffer on the side) ----------------
__global__ void f32_to_bf16(const float* __restrict__ in, ushort* __restrict__ out, int n4,
                            int* __restrict__ zbuf, int nz) {
    int i = blockIdx.x * blockDim.x + threadIdx.x;
    if (i < nz) zbuf[i] = 0;
    if (i >= n4) return;
    float4 v = reinterpret_cast<const float4*>(in)[i];
    ushort4 o;
    o.x = f2bf(v.x); o.y = f2bf(v.y); o.z = f2bf(v.z); o.w = f2bf(v.w);
    reinterpret_cast<ushort4*>(out)[i] = o;
}

// ---------------- weight convert+transpose ----------------
__global__ void conv_transpose_bf16(const float* __restrict__ W, ushort* __restrict__ Wt,
                                    int K, int N) {
    int i = blockIdx.x * blockDim.x + threadIdx.x;
    if (i >= K * N) return;
    int k = i / N, n = i % N;
    Wt[(size_t)n * K + k] = f2bf(W[i]);
}

// ---------------- MFMA bf16 GEMM (optional fused sum/sumsq stats) ----------------
template <bool BF16OUT, bool STATS>
__global__ __launch_bounds__(256)
void gemm_bf16_mfma(const ushort* __restrict__ A, const ushort* __restrict__ Bt,
                    const float* __restrict__ bias, float* __restrict__ C,
                    ushort* __restrict__ Cb, float* __restrict__ Sp, int M, int N, int K) {
    constexpr int BM = 128, BN = 128, BK = 32;
    constexpr int LDK = BK + 8;
    __shared__ ushort As[BM * LDK];
    __shared__ ushort Bs[BN * LDK];
    int tid = threadIdx.x;
    int wid = tid >> 6, lane = tid & 63;
    int wr = wid >> 1, wc = wid & 1;
    int bm = blockIdx.x * BM, bn = blockIdx.y * BN;
    int lg = lane >> 4, lm = lane & 15;
    f32x4 zero = {0.f, 0.f, 0.f, 0.f};
    f32x4 acc[4][4];
#pragma unroll
    for (int m = 0; m < 4; ++m)
#pragma unroll
        for (int n = 0; n < 4; ++n) acc[m][n] = zero;

    for (int k0 = 0; k0 < K; k0 += BK) {
#pragma unroll
        for (int it = 0; it < 2; ++it) {
            int task = tid * 2 + it;
            int row = task >> 2, c8 = (task & 3) * 8;
            int gm = bm + row;
            bf16x8 v = {0, 0, 0, 0, 0, 0, 0, 0};
            if (gm < M) v = *(const bf16x8*)&A[(size_t)gm * K + k0 + c8];
            *(bf16x8*)&As[row * LDK + c8] = v;
            int gn = bn + row;
            bf16x8 w = {0, 0, 0, 0, 0, 0, 0, 0};
            if (gn < N) w = *(const bf16x8*)&Bt[(size_t)gn * K + k0 + c8];
            *(bf16x8*)&Bs[row * LDK + c8] = w;
        }
        __syncthreads();
        bf16x8 af[4], bfr[4];
#pragma unroll
        for (int m = 0; m < 4; ++m)
            af[m] = *(bf16x8*)&As[(wr * 64 + m * 16 + lm) * LDK + lg * 8];
#pragma unroll
        for (int n = 0; n < 4; ++n)
            bfr[n] = *(bf16x8*)&Bs[(wc * 64 + n * 16 + lm) * LDK + lg * 8];
#pragma unroll
        for (int m = 0; m < 4; ++m)
#pragma unroll
            for (int n = 0; n < 4; ++n)
                acc[m][n] = __builtin_amdgcn_mfma_f32_16x16x32_bf16(af[m], bfr[n], acc[m][n], 0, 0, 0);
        __syncthreads();
    }
    float ls = 0.f, lq = 0.f;
#pragma unroll
    for (int m = 0; m < 4; ++m) {
#pragma unroll
        for (int n = 0; n < 4; ++n) {
            int col = bn + wc * 64 + n * 16 + lm;
            float bv = bias ? bias[col] : 0.f;
#pragma unroll
            for (int r = 0; r < 4; ++r) {
                int row = bm + wr * 64 + m * 16 + lg * 4 + r;
                if (row < M) {
                    float val = acc[m][n][r] + bv;
                    if (BF16OUT) Cb[(size_t)row * N + col] = f2bf(val);
                    else         C[(size_t)row * N + col] = val;
                    if (STATS) { ls += val; lq += val * val; }
                }
            }
        }
    }
    if (STATS) {
        __shared__ float rs[256], rq[256];
        rs[tid] = ls; rq[tid] = lq;
        __syncthreads();
        for (int off = 128; off > 0; off >>= 1) {
            if (tid < off) { rs[tid] += rs[tid + off]; rq[tid] += rq[tid + off]; }
            __syncthreads();
        }
        if (tid == 0) {
            int b = blockIdx.y * gridDim.x + blockIdx.x;
            Sp[2 * b] = rs[0];
            Sp[2 * b + 1] = rq[0];
        }
    }
}

// ---------------- CSR build ----------------
__global__ void count_deg(const int* __restrict__ dst, const int* __restrict__ mask, int E,
                          int* __restrict__ cnt) {
    int e = blockIdx.x * blockDim.x + threadIdx.x;
    if (e >= E) return;
    if (mask && !mask[e]) return;
    atomicAdd(&cnt[dst[e]], 1);
}

// single 1024-thread block: register-resident exclusive scan of counts (n <= 20480)
__global__ void scan_all(const int* __restrict__ cnt, int n, int* __restrict__ rowstart,
                         int* __restrict__ cursor, float* __restrict__ deg,
                         float* __restrict__ dinv) {
    int t = threadIdx.x;
    int lane = t & 63, w = t >> 6;
    int base = t * KPT;
    int c[KPT];
    int s = 0;
#pragma unroll
    for (int i = 0; i < KPT; ++i) {
        int idx = base + i;
        c[i] = (idx < n) ? cnt[idx] : 0;
        s += c[i];
    }
    int si = s;
    for (int off = 1; off < 64; off <<= 1) {
        int vv = __shfl_up(si, off);
        if (lane >= off) si += vv;
    }
    __shared__ int wsum[16];
    if (lane == 63) wsum[w] = si;
    __syncthreads();
    int wpre = 0;
    for (int i = 0; i < w; ++i) wpre += wsum[i];
    int total = 0;
    for (int i = 0; i < 16; ++i) total += wsum[i];
    int excl = wpre + si - s;
#pragma unroll
    for (int i = 0; i < KPT; ++i) {
        int idx = base + i;
        if (idx < n) {
            rowstart[idx] = excl;
            cursor[idx] = excl;
            float dg = (float)c[i] + 2.0f;
            deg[idx] = dg;
            dinv[idx] = rsqrtf(dg);
        }
        excl += c[i];
    }
    if (t == 0) rowstart[n] = total;
}

__global__ void csr_scatter(const int* __restrict__ src, const int* __restrict__ dst,
                            const int* __restrict__ mask, int E,
                            int* __restrict__ cursor, int* __restrict__ csr_src) {
    int e = blockIdx.x * blockDim.x + threadIdx.x;
    if (e >= E) return;
    if (mask && !mask[e]) return;
    int pos = atomicAdd(&cursor[dst[e]], 1);
    csr_src[pos] = src[e];
}

// ---------------- stage-1 aggregation: 8-deep pipelined gather (bf16 in/out) ----------------
__global__ void aggregate_xb(const int* __restrict__ rowstart, const int* __restrict__ csr_src,
                             const float* __restrict__ deg, const float* __restrict__ dinv,
                             const ushort* __restrict__ xb, ushort* __restrict__ out, int n) {
    int node = blockIdx.x * (blockDim.x >> 6) + ((int)threadIdx.x >> 6);
    if (node >= n) return;
    int lane = threadIdx.x & 63;
    int beg = rowstart[node], end = rowstart[node + 1];
    float di = dinv[node];
    float4 acc = make_float4(0.f, 0.f, 0.f, 0.f);
    int j = beg;
    for (; j + 8 <= end; j += 8) {
        int s[8];
#pragma unroll
        for (int u = 0; u < 8; ++u) s[u] = csr_src[j + u];
        float c[8];
#pragma unroll
        for (int u = 0; u < 8; ++u) c[u] = dinv[s[u]] * di;
        ushort4 t[8];
#pragma unroll
        for (int u = 0; u < 8; ++u)
            t[u] = reinterpret_cast<const ushort4*>(&xb[(size_t)s[u] * CIN])[lane];
#pragma unroll
        for (int u = 0; u < 8; ++u) {
            acc.x += c[u] * bf2f(t[u].x);
            acc.y += c[u] * bf2f(t[u].y);
            acc.z += c[u] * bf2f(t[u].z);
            acc.w += c[u] * bf2f(t[u].w);
        }
    }
    for (; j < end; ++j) {
        int s = csr_src[j];
        float coef = dinv[s] * di;
        ushort4 t = reinterpret_cast<const ushort4*>(&xb[(size_t)s * CIN])[lane];
        acc.x += coef * bf2f(t.x);
        acc.y += coef * bf2f(t.y);
        acc.z += coef * bf2f(t.z);
        acc.w += coef * bf2f(t.w);
    }
    float self = 2.0f / deg[node];
    ushort4 t = reinterpret_cast<const ushort4*>(&xb[(size_t)node * CIN])[lane];
    acc.x += self * bf2f(t.x);
    acc.y += self * bf2f(t.y);
    acc.z += self * bf2f(t.z);
    acc.w += self * bf2f(t.w);
    ushort4 o;
    o.x = f2bf(acc.x); o.y = f2bf(acc.y); o.z = f2bf(acc.z); o.w = f2bf(acc.w);
    reinterpret_cast<ushort4*>(&out[(size_t)node * CIN])[lane] = o;
}

// ---------------- stage-2 aggregation: 8-deep gather, f32 out + bias + self + fused stats ----------------
__global__ void aggregate_csr_bf(const int* __restrict__ rowstart, const int* __restrict__ csr_src,
                                 const float* __restrict__ deg, const float* __restrict__ dinv,
                                 const ushort* __restrict__ xWb, const float* __restrict__ b,
                                 float* __restrict__ out, float* __restrict__ Sp, int n) {
    int node = blockIdx.x * (blockDim.x >> 6) + ((int)threadIdx.x >> 6);
    bool valid = node < n;
    int lane = threadIdx.x & 63;
    float ls = 0.f, lq = 0.f;
    if (valid) {
        int beg = rowstart[node], end = rowstart[node + 1];
        float di = dinv[node];
        float4 acc = make_float4(0.f, 0.f, 0.f, 0.f);
        int j = beg;
        for (; j + 8 <= end; j += 8) {
            int s[8];
#pragma unroll
            for (int u = 0; u < 8; ++u) s[u] = csr_src[j + u];
            float c[8];
#pragma unroll
            for (int u = 0; u < 8; ++u) c[u] = dinv[s[u]] * di;
            ushort4 t[8];
#pragma unroll
            for (int u = 0; u < 8; ++u)
                t[u] = reinterpret_cast<const ushort4*>(&xWb[(size_t)s[u] * C2])[lane];
#pragma unroll
            for (int u = 0; u < 8; ++u) {
                acc.x += c[u] * bf2f(t[u].x);
                acc.y += c[u] * bf2f(t[u].y);
                acc.z += c[u] * bf2f(t[u].z);
                acc.w += c[u] * bf2f(t[u].w);
            }
        }
        for (; j < end; ++j) {
            int s = csr_src[j];
            float coef = dinv[s] * di;
            ushort4 t = reinterpret_cast<const ushort4*>(&xWb[(size_t)s * C2])[lane];
            acc.x += coef * bf2f(t.x);
            acc.y += coef * bf2f(t.y);
            acc.z += coef * bf2f(t.z);
            acc.w += coef * bf2f(t.w);
        }
        float self = 2.0f / deg[node];
        ushort4 t = reinterpret_cast<const ushort4*>(&xWb[(size_t)node * C2])[lane];
        float4 bb = reinterpret_cast<const float4*>(b)[lane];
        float4 o;
        o.x = acc.x + self * bf2f(t.x) + bb.x;
        o.y = acc.y + self * bf2f(t.y) + bb.y;
        o.z = acc.z + self * bf2f(t.z) + bb.z;
        o.w = acc.w + self * bf2f(t.w) + bb.w;
        reinterpret_cast<float4*>(&out[(size_t)node * C2])[lane] = o;
        ls = o.x + o.y + o.z + o.w;
        lq = o.x * o.x + o.y * o.y + o.z * o.z + o.w * o.w;
    }
    __shared__ float rs[256], rq[256];
    rs[threadIdx.x] = ls; rq[threadIdx.x] = lq;
    __syncthreads();
    for (int off = 128; off > 0; off >>= 1) {
        if ((int)threadIdx.x < off) {
            rs[threadIdx.x] += rs[threadIdx.x + off];
            rq[threadIdx.x] += rq[threadIdx.x + off];
        }
        __syncthreads();
    }
    if (threadIdx.x == 0) {
        Sp[2 * blockIdx.x] = rs[0];
        Sp[2 * blockIdx.x + 1] = rq[0];
    }
}

// ---------------- norm+relu scores (stats folded in; h read-only) ----------------
template <int C>
__global__ void norm_scores(const float* __restrict__ h, int n, const float* __restrict__ Sp,
                            int nb, float inv_cnt, const float* __restrict__ lnw,
                            const float* __restrict__ lnb, const float* __restrict__ wrel,
                            const float* __restrict__ brel, const float* __restrict__ wroot,
                            float* __restrict__ r, float* __restrict__ score) {
    float mean, istd;
    block_stats(Sp, nb, inv_cnt, mean, istd);
    int node = blockIdx.x * (blockDim.x >> 6) + ((int)threadIdx.x >> 6);
    if (node >= n) return;
    int lane = threadIdx.x & 63;
    const float4* row = reinterpret_cast<const float4*>(&h[(size_t)node * C]);
    float sr = 0.f, st = 0.f;
#pragma unroll
    for (int kk = 0; kk < C / 256; ++kk) {
        int idx = lane + 64 * kk;
        float4 v = row[idx];
        float4 w = reinterpret_cast<const float4*>(lnw)[idx];
        float4 bb = reinterpret_cast<const float4*>(lnb)[idx];
        float4 w4 = reinterpret_cast<const float4*>(wrel)[idx];
        float4 o4 = reinterpret_cast<const float4*>(wroot)[idx];
        v.x = fmaxf((v.x - mean) * istd * w.x + bb.x, 0.f);
        v.y = fmaxf((v.y - mean) * istd * w.y + bb.y, 0.f);
        v.z = fmaxf((v.z - mean) * istd * w.z + bb.z, 0.f);
        v.w = fmaxf((v.w - mean) * istd * w.w + bb.w, 0.f);
        sr += v.x * w4.x + v.y * w4.y + v.z * w4.z + v.w * w4.w;
        st += v.x * o4.x + v.y * o4.y + v.z * o4.z + v.w * o4.w;
    }
    for (int off = 32; off > 0; off >>= 1) {
        sr += __shfl_down(sr, off);
        st += __shfl_down(st, off);
    }
    if (lane == 0) {
        r[node] = sr;
        score[node] = st + brel[0];
    }
}

// ---------------- gather score over CSR + keyify ----------------
__global__ void gather_score_key(const int* __restrict__ rowstart, const int* __restrict__ csr_src,
                                 const float* __restrict__ r, float* __restrict__ score,
                                 unsigned* __restrict__ key, int n) {
    int i = blockIdx.x * blockDim.x + threadIdx.x;
    if (i >= n) return;
    float s = score[i];
    int beg = rowstart[i], end = rowstart[i + 1];
    int j = beg;
    for (; j + 4 <= end; j += 4) {
        int s0 = csr_src[j], s1 = csr_src[j + 1], s2 = csr_src[j + 2], s3 = csr_src[j + 3];
        s += r[s0] + r[s1] + r[s2] + r[s3];
    }
    for (; j < end; ++j) s += r[csr_src[j]];
    score[i] = s;
    unsigned u = __float_as_uint(s);
    key[i] = (u & 0x80000000u) ? ~u : (u | 0x80000000u);
}

// ---------------- full top-k in ONE kernel: radix select + deterministic compact ----------------
// 1024 threads; keys register-resident (KPT contiguous per thread, n <= 20480).
__global__ void topk_all(const unsigned* __restrict__ key, int n, unsigned k,
                         int* __restrict__ kept, int* __restrict__ inv) {
    __shared__ unsigned hist[256];
    __shared__ unsigned wsum[16];
    __shared__ unsigned s_pref, s_rem;
    __shared__ int wgs[16], wes[16];
    int t = threadIdx.x;
    int lane = t & 63, w = t >> 6;
    int base = t * KPT;

    unsigned kv[KPT];
#pragma unroll
    for (int i = 0; i < KPT; ++i) {
        int idx = base + i;
        kv[i] = (idx < n) ? key[idx] : 0u;
    }
    if (t < 256) hist[t] = 0u;
    if (t == 0) { s_pref = 0u; s_rem = k; }
    __syncthreads();

    unsigned pref = 0u, msk = 0u, rem = k;
    for (int pass = 0; pass < 4; ++pass) {
        int shift = 24 - 8 * pass;
#pragma unroll
        for (int i = 0; i < KPT; ++i) {
            int idx = base + i;
            if (idx < n && (kv[i] & msk) == pref)
                atomicAdd(&hist[(kv[i] >> shift) & 255u], 1u);
        }
        __syncthreads();
        unsigned val = (t < 256) ? hist[255 - t] : 0u;   // descending order
        unsigned si = val;
        for (int off = 1; off < 64; off <<= 1) {
            unsigned vv = __shfl_up(si, off);
            if (lane >= off) si += vv;
        }
        if (lane == 63 && w < 4) wsum[w] = si;
        __syncthreads();
        if (t < 256) {
            unsigned wpre = 0u;
            for (int i = 0; i < w; ++i) wpre += wsum[i];
            unsigned incl = wpre + si;
            unsigned excl = incl - val;
            if (excl < rem && rem <= incl) {
                s_pref = pref | ((unsigned)(255 - t) << shift);
                s_rem = rem - excl;
            }
        }
        if (t < 256) hist[t] = 0u;
        __syncthreads();
        pref = s_pref;
        rem = s_rem;
        msk = 0xFFFFFFFFu << shift;
    }
    unsigned thr = pref;
    int tie = (int)rem;

    // deterministic compact: prefix of (key>thr) and (key==thr) across the block
    int gl[KPT], el[KPT];
    int gs = 0, es = 0;
#pragma unroll
    for (int i = 0; i < KPT; ++i) {
        int idx = base + i;
        gl[i] = 0; el[i] = 0;
        if (idx < n) {
            gl[i] = (kv[i] > thr);
            el[i] = (kv[i] == thr);
        }
        gs += gl[i]; es += el[i];
    }
    int gi = gs, ei = es;
    for (int off = 1; off < 64; off <<= 1) {
        int gg = __shfl_up(gi, off), ee = __shfl_up(ei, off);
        if (lane >= off) { gi += gg; ei += ee; }
    }
    if (lane == 63) { wgs[w] = gi; wes[w] = ei; }
    __syncthreads();
    int gw = 0, ew = 0;
    for (int i = 0; i < w; ++i) { gw += wgs[i]; ew += wes[i]; }
    int gp = gw + gi - gs;
    int ep = ew + ei - es;
#pragma unroll
    for (int i = 0; i < KPT; ++i) {
        int idx = base + i;
        if (idx < n) {
            int keep = gl[i] | (el[i] & ((ep < tie) ? 1 : 0));
            kept[idx] = keep;
            inv[idx] = gp + ((ep < tie) ? ep : tie);
        }
        gp += gl[i]; ep += el[i];
    }
}

// ---------------- pool apply: stats folded; wave per node; bf16 out (C=512) ----------------
__global__ void pool_apply_rows(const float* __restrict__ h, const float* __restrict__ score,
                                const int* __restrict__ kept, const int* __restrict__ inv,
                                int n, const float* __restrict__ Sp, int nb, float inv_cnt,
                                const float* __restrict__ lnw, const float* __restrict__ lnb,
                                ushort* __restrict__ hp) {
    float mean, istd;
    block_stats(Sp, nb, inv_cnt, mean, istd);
    int node = blockIdx.x * (blockDim.x >> 6) + ((int)threadIdx.x >> 6);
    if (node >= n) return;
    if (!kept[node]) return;
    int lane = threadIdx.x & 63;
    float tw = tanhf(score[node]);
    const float4* src = reinterpret_cast<const float4*>(&h[(size_t)node * C1]);
    ushort4* dst = reinterpret_cast<ushort4*>(&hp[(size_t)inv[node] * C1]);
#pragma unroll
    for (int v = 0; v < 2; ++v) {
        int idx = lane + 64 * v;
        float4 a = src[idx];
        float4 w = reinterpret_cast<const float4*>(lnw)[idx];
        float4 bb = reinterpret_cast<const float4*>(lnb)[idx];
        ushort4 o;
        o.x = f2bf(fmaxf((a.x - mean) * istd * w.x + bb.x, 0.f) * tw);
        o.y = f2bf(fmaxf((a.y - mean) * istd * w.y + bb.y, 0.f) * tw);
        o.z = f2bf(fmaxf((a.z - mean) * istd * w.z + bb.z, 0.f) * tw);
        o.w = f2bf(fmaxf((a.w - mean) * istd * w.w + bb.w, 0.f) * tw);
        dst[idx] = o;
    }
}

// ---------------- edge relabel (+ zero next stage's count buffer) ----------------
__global__ void edge_relabel(const int* __restrict__ src, const int* __restrict__ dst, int E,
                             const int* __restrict__ kept, const int* __restrict__ inv,
                             int* __restrict__ src2, int* __restrict__ dst2,
                             int* __restrict__ mask2, int* __restrict__ zbuf, int nz) {
    int e = blockIdx.x * blockDim.x + threadIdx.x;
    if (e < nz) zbuf[e] = 0;
    if (e >= E) return;
    int s = src[e], d = dst[e];
    int m = kept[s] & kept[d];
    mask2[e] = m;
    src2[e] = m ? inv[s] : 0;
    dst2[e] = m ? inv[d] : 0;
}

// ---------------- masked weighted column mean (stats folded; norm+relu on the fly) ----------------
__global__ void colmean_part(const float* __restrict__ h, const float* __restrict__ score,
                             const int* __restrict__ kept, int n, const float* __restrict__ Sp,
                             int nb, float inv_cnt, const float* __restrict__ lnw,
                             const float* __restrict__ lnb, float* __restrict__ Gp) {
    float mean, istd;
    block_stats(Sp, nb, inv_cnt, mean, istd);
    __shared__ float w[CM_ROWS];
    int i0 = blockIdx.x * CM_ROWS;
    int t = threadIdx.x;
    float wn = lnw[t] * istd;
    float bn = lnb[t] - mean * wn;
    for (int i = t; i < CM_ROWS; i += 256) {
        int idx = i0 + i;
        w[i] = (idx < n && kept[idx]) ? tanhf(score[idx]) : 0.f;
    }
    __syncthreads();
    float acc = 0.f;
    int rows = min(CM_ROWS, n - i0);
#pragma unroll 8
    for (int ri = 0; ri < rows; ++ri)
        acc = fmaf(w[ri], fmaxf(fmaf(h[(size_t)(i0 + ri) * C2 + t], wn, bn), 0.f), acc);
    Gp[blockIdx.x * 256 + t] = acc;
}

// ---------------- fused: fold colmean partials + final GEMV ----------------
__global__ void final_fused(const float* __restrict__ Gp, int nb, float invk,
                            const float* __restrict__ Wf, const float* __restrict__ bf,
                            float* __restrict__ out) {
    __shared__ float g[256];
    int t = threadIdx.x;  // 256
    float s = 0.f;
    for (int b = 0; b < nb; ++b) s += Gp[b * 256 + t];
    g[t] = s * invk;
    __syncthreads();
    if (t < NOUT) {
        float acc = bf[t];
        for (int c = 0; c < 256; ++c) acc = fmaf(g[c], Wf[c * NOUT + t], acc);
        out[t] = acc;
    }
}

// =======================================================================================
extern "C" void kernel_launch(void* const* d_in, const int* in_sizes, int n_in,
                              void* d_out, int out_size, void* d_ws, size_t ws_size,
                              hipStream_t stream) {
    const float* x      = (const float*)d_in[0];
    const int*   ei     = (const int*)d_in[1];
    const float* W1     = (const float*)d_in[2];
    const float* b1     = (const float*)d_in[3];
    const float* ln1w   = (const float*)d_in[4];
    const float* ln1b   = (const float*)d_in[5];
    const float* p1wrel = (const float*)d_in[6];
    const float* p1brel = (const float*)d_in[7];
    const float* p1wroot= (const float*)d_in[8];
    const float* W2     = (const float*)d_in[9];
    const float* b2     = (const float*)d_in[10];
    const float* ln2w   = (const float*)d_in[11];
    const float* ln2b   = (const float*)d_in[12];
    const float* p2wrel = (const float*)d_in[13];
    const float* p2brel = (const float*)d_in[14];
    const float* p2wroot= (const float*)d_in[15];
    const float* Wf     = (const float*)d_in[16];
    const float* bf     = (const float*)d_in[17];
    float* out = (float*)d_out;
    char* ws = (char*)d_ws;

    const int* src1 = ei;
    const int* dst1 = ei + NE;

    // ---- workspace layout (bytes) ----
    const size_t o0     = 0;          // 40.96 MB: h1 f32; later h2 f32 @+0, xW2b bf16 @+10,240,000
    const size_t o1     = 40960000;   // 10.24 MB: aggb bf16; later h1pb bf16
    const size_t oXb    = 51200000;   // 10,240,000 : xb bf16
    const size_t oW1t   = 61440000;
    const size_t oW2t   = 61702144;
    const size_t oSrc2  = 61964288;
    const size_t oDst2  = 63244288;
    const size_t oMask2 = 64524288;
    const size_t oCsr   = 65804288;
    const size_t oRow   = 67084288;
    const size_t oCur   = 67164352;
    const size_t oDeg   = 67244352;
    const size_t oDinv  = 67324352;
    const size_t oR     = 67404352;
    const size_t oScore1= 67484352;
    const size_t oKeyu  = 67564352;
    const size_t oKept  = 67644352;
    const size_t oInv   = 67724352;
    const size_t oScore2= 67804352;
    const size_t oKeyu2 = 67844352;
    const size_t oKept2 = 67884352;
    const size_t oInv2  = 67924352;
    const size_t oGp    = 68232256;   // 81,920 : colmean partials
    const size_t oSp    = 68314176;   // 32,768 : stats partials

    float*  h1    = (float*)(ws + o0);
    float*  h2    = (float*)(ws + o0);
    ushort* xW2b  = (ushort*)(ws + o0 + 10240000);
    ushort* aggb  = (ushort*)(ws + o1);
    ushort* h1pb  = (ushort*)(ws + o1);
    ushort* xb    = (ushort*)(ws + oXb);
    ushort* W1t   = (ushort*)(ws + oW1t);
    ushort* W2t   = (ushort*)(ws + oW2t);
    int*    src2  = (int*)(ws + oSrc2);
    int*    dst2  = (int*)(ws + oDst2);
    int*    mask2 = (int*)(ws + oMask2);
    int*    csr   = (int*)(ws + oCsr);
    int*    row   = (int*)(ws + oRow);
    int*    cur   = (int*)(ws + oCur);
    float*  deg   = (float*)(ws + oDeg);
    float*  dinv  = (float*)(ws + oDinv);
    float*  r     = (float*)(ws + oR);
    float*  score1= (float*)(ws + oScore1);
    unsigned* keyu  = (unsigned*)(ws + oKeyu);
    int*    kept  = (int*)(ws + oKept);
    int*    inv   = (int*)(ws + oInv);
    float*  score2= (float*)(ws + oScore2);
    unsigned* keyu2 = (unsigned*)(ws + oKeyu2);
    int*    kept2 = (int*)(ws + oKept2);
    int*    inv2  = (int*)(ws + oInv2);
    float*  Gp    = (float*)(ws + oGp);
    float*  Sp    = (float*)(ws + oSp);

    const int nbc = cdiv(K1, CM_ROWS);  // 79
    const int g1x = cdiv(N1, 128), g1y = C1 / 128;   // stat blocks (628)
    const int agg2b = cdiv(K1, 4);      // 2500 stat blocks
    const float ic1 = 1.f / ((float)N1 * C1);
    const float ic2 = 1.f / ((float)K1 * C2);

    // ================= Stage 1 =================
    f32_to_bf16<<<cdiv(N1 * CIN / 4, 256), 256, 0, stream>>>(x, xb, N1 * CIN / 4, cur, N1);
    count_deg<<<cdiv(NE, 256), 256, 0, stream>>>(dst1, nullptr, NE, cur);
    scan_all<<<1, 1024, 0, stream>>>(cur, N1, row, cur, deg, dinv);
    csr_scatter<<<cdiv(NE, 256), 256, 0, stream>>>(src1, dst1, nullptr, NE, cur, csr);

    aggregate_xb<<<cdiv(N1, 4), 256, 0, stream>>>(row, csr, deg, dinv, xb, aggb, N1);

    conv_transpose_bf16<<<cdiv(CIN * C1, 256), 256, 0, stream>>>(W1, W1t, CIN, C1);
    gemm_bf16_mfma<false, true><<<dim3(g1x, g1y), 256, 0, stream>>>(
        aggb, W1t, b1, h1, nullptr, Sp, N1, C1, CIN);

    norm_scores<C1><<<cdiv(N1, 4), 256, 0, stream>>>(h1, N1, Sp, g1x * g1y, ic1,
                                                     ln1w, ln1b, p1wrel, p1brel, p1wroot, r, score1);
    gather_score_key<<<cdiv(N1, 256), 256, 0, stream>>>(row, csr, r, score1, keyu, N1);
    topk_all<<<1, 1024, 0, stream>>>(keyu, N1, K1, kept, inv);

    pool_apply_rows<<<cdiv(N1, 4), 256, 0, stream>>>(h1, score1, kept, inv, N1, Sp, g1x * g1y,
                                                     ic1, ln1w, ln1b, h1pb);
    edge_relabel<<<cdiv(NE, 256), 256, 0, stream>>>(src1, dst1, NE, kept, inv,
                                                    src2, dst2, mask2, cur, K1);

    // ================= Stage 2 =================
    conv_transpose_bf16<<<cdiv(C1 * C2, 256), 256, 0, stream>>>(W2, W2t, C1, C2);
    gemm_bf16_mfma<true, false><<<dim3(cdiv(K1, 128), C2 / 128), 256, 0, stream>>>(
        h1pb, W2t, nullptr, nullptr, xW2b, nullptr, K1, C2, C1);

    count_deg<<<cdiv(NE, 256), 256, 0, stream>>>(dst2, mask2, NE, cur);
    scan_all<<<1, 1024, 0, stream>>>(cur, K1, row, cur, deg, dinv);
    csr_scatter<<<cdiv(NE, 256), 256, 0, stream>>>(src2, dst2, mask2, NE, cur, csr);

    aggregate_csr_bf<<<agg2b, 256, 0, stream>>>(row, csr, deg, dinv, xW2b, b2, h2, Sp, K1);

    norm_scores<C2><<<cdiv(K1, 4), 256, 0, stream>>>(h2, K1, Sp, agg2b, ic2,
                                                     ln2w, ln2b, p2wrel, p2brel, p2wroot, r, score2);
    gather_score_key<<<cdiv(K1, 256), 256, 0, stream>>>(row, csr, r, score2, keyu2, K1);
    topk_all<<<1, 1024, 0, stream>>>(keyu2, K1, K2, kept2, inv2);

    // ================= readout =================
    colmean_part<<<nbc, 256, 0, stream>>>(h2, score2, kept2, K1, Sp, agg2b, ic2,
                                          ln2w, ln2b, Gp);
    final_fused<<<1, 256, 0, stream>>>(Gp, nbc, 1.f / (float)K2, Wf, bf, out);
}

// Round 13
// 293.931 us; speedup vs baseline: 1.2580x; 1.2580x over previous
//
#include <hip/hip_runtime.h>
#include <math.h>

#define N1 20000
#define NE 320000
#define CIN 256
#define C1 512
#define C2 256
#define K1 10000
#define K2 5000
#define NOUT 128
#define EPSV 1e-5f
#define CM_ROWS 128

typedef __attribute__((ext_vector_type(8))) short bf16x8;
typedef __attribute__((ext_vector_type(4))) float f32x4;

static inline unsigned cdiv(unsigned a, unsigned b) { return (a + b - 1) / b; }

__device__ inline ushort f2bf(float f) {
    unsigned u = __float_as_uint(f);
    unsigned r = u + 0x7FFFu + ((u >> 16) & 1u);
    return (ushort)(r >> 16);
}
__device__ inline float bf2f(ushort u) { return __uint_as_float(((unsigned)u) << 16); }

// ---------------- f32 -> bf16 (+ zero an int buffer on the side) ----------------
__global__ void f32_to_bf16(const float* __restrict__ in, ushort* __restrict__ out, int n4,
                            int* __restrict__ zbuf, int nz) {
    int i = blockIdx.x * blockDim.x + threadIdx.x;
    if (i < nz) zbuf[i] = 0;
    if (i >= n4) return;
    float4 v = reinterpret_cast<const float4*>(in)[i];
    ushort4 o;
    o.x = f2bf(v.x); o.y = f2bf(v.y); o.z = f2bf(v.z); o.w = f2bf(v.w);
    reinterpret_cast<ushort4*>(out)[i] = o;
}

// ---------------- weight convert+transpose ----------------
__global__ void conv_transpose_bf16(const float* __restrict__ W, ushort* __restrict__ Wt,
                                    int K, int N) {
    int i = blockIdx.x * blockDim.x + threadIdx.x;
    if (i >= K * N) return;
    int k = i / N, n = i % N;
    Wt[(size_t)n * K + k] = f2bf(W[i]);
}

// ---------------- MFMA bf16 GEMM (optional fused sum/sumsq stats) ----------------
template <bool BF16OUT, bool STATS>
__global__ __launch_bounds__(256)
void gemm_bf16_mfma(const ushort* __restrict__ A, const ushort* __restrict__ Bt,
                    const float* __restrict__ bias, float* __restrict__ C,
                    ushort* __restrict__ Cb, float* __restrict__ Sp, int M, int N, int K) {
    constexpr int BM = 128, BN = 128, BK = 32;
    constexpr int LDK = BK + 8;
    __shared__ ushort As[BM * LDK];
    __shared__ ushort Bs[BN * LDK];
    int tid = threadIdx.x;
    int wid = tid >> 6, lane = tid & 63;
    int wr = wid >> 1, wc = wid & 1;
    int bm = blockIdx.x * BM, bn = blockIdx.y * BN;
    int lg = lane >> 4, lm = lane & 15;
    f32x4 zero = {0.f, 0.f, 0.f, 0.f};
    f32x4 acc[4][4];
#pragma unroll
    for (int m = 0; m < 4; ++m)
#pragma unroll
        for (int n = 0; n < 4; ++n) acc[m][n] = zero;

    for (int k0 = 0; k0 < K; k0 += BK) {
#pragma unroll
        for (int it = 0; it < 2; ++it) {
            int task = tid * 2 + it;
            int row = task >> 2, c8 = (task & 3) * 8;
            int gm = bm + row;
            bf16x8 v = {0, 0, 0, 0, 0, 0, 0, 0};
            if (gm < M) v = *(const bf16x8*)&A[(size_t)gm * K + k0 + c8];
            *(bf16x8*)&As[row * LDK + c8] = v;
            int gn = bn + row;
            bf16x8 w = {0, 0, 0, 0, 0, 0, 0, 0};
            if (gn < N) w = *(const bf16x8*)&Bt[(size_t)gn * K + k0 + c8];
            *(bf16x8*)&Bs[row * LDK + c8] = w;
        }
        __syncthreads();
        bf16x8 af[4], bfr[4];
#pragma unroll
        for (int m = 0; m < 4; ++m)
            af[m] = *(bf16x8*)&As[(wr * 64 + m * 16 + lm) * LDK + lg * 8];
#pragma unroll
        for (int n = 0; n < 4; ++n)
            bfr[n] = *(bf16x8*)&Bs[(wc * 64 + n * 16 + lm) * LDK + lg * 8];
#pragma unroll
        for (int m = 0; m < 4; ++m)
#pragma unroll
            for (int n = 0; n < 4; ++n)
                acc[m][n] = __builtin_amdgcn_mfma_f32_16x16x32_bf16(af[m], bfr[n], acc[m][n], 0, 0, 0);
        __syncthreads();
    }
    float ls = 0.f, lq = 0.f;
#pragma unroll
    for (int m = 0; m < 4; ++m) {
#pragma unroll
        for (int n = 0; n < 4; ++n) {
            int col = bn + wc * 64 + n * 16 + lm;
            float bv = bias ? bias[col] : 0.f;
#pragma unroll
            for (int r = 0; r < 4; ++r) {
                int row = bm + wr * 64 + m * 16 + lg * 4 + r;
                if (row < M) {
                    float val = acc[m][n][r] + bv;
                    if (BF16OUT) Cb[(size_t)row * N + col] = f2bf(val);
                    else         C[(size_t)row * N + col] = val;
                    if (STATS) { ls += val; lq += val * val; }
                }
            }
        }
    }
    if (STATS) {
        __shared__ float rs[256], rq[256];
        rs[tid] = ls; rq[tid] = lq;
        __syncthreads();
        for (int off = 128; off > 0; off >>= 1) {
            if (tid < off) { rs[tid] += rs[tid + off]; rq[tid] += rq[tid + off]; }
            __syncthreads();
        }
        if (tid == 0) {
            int b = blockIdx.y * gridDim.x + blockIdx.x;
            Sp[2 * b] = rs[0];
            Sp[2 * b + 1] = rq[0];
        }
    }
}

// ---------------- CSR build ----------------
__global__ void count_deg(const int* __restrict__ dst, const int* __restrict__ mask, int E,
                          int* __restrict__ cnt) {
    int e = blockIdx.x * blockDim.x + threadIdx.x;
    if (e >= E) return;
    if (mask && !mask[e]) return;
    atomicAdd(&cnt[dst[e]], 1);
}

__global__ void dp_partial(const int* __restrict__ cnt, int n, int* __restrict__ part) {
    int base = blockIdx.x * 1024 + (int)threadIdx.x * 4;
    int s = 0;
#pragma unroll
    for (int t = 0; t < 4; ++t) {
        int i = base + t;
        if (i < n) s += cnt[i];
    }
    for (int off = 32; off > 0; off >>= 1) s += __shfl_down(s, off);
    __shared__ int sg[4];
    int wid = threadIdx.x >> 6;
    if ((threadIdx.x & 63) == 0) sg[wid] = s;
    __syncthreads();
    if (threadIdx.x == 0) part[blockIdx.x] = sg[0] + sg[1] + sg[2] + sg[3];
}

__global__ void scan64k(int nb, int* __restrict__ part, int* __restrict__ row_n) {
    int lane = threadIdx.x;
    int v0 = (lane < nb) ? part[lane] : 0;
    int v = v0;
    for (int off = 1; off < 64; off <<= 1) {
        int vv = __shfl_up(v, off);
        if (lane >= off) v += vv;
    }
    if (lane == nb - 1) row_n[0] = v;
    if (lane < nb) part[lane] = v - v0;
}

__global__ void dp_final(const int* __restrict__ cnt, int n, const int* __restrict__ part,
                         int* __restrict__ rowstart, int* __restrict__ cursor,
                         float* __restrict__ deg, float* __restrict__ dinv) {
    int base = blockIdx.x * 1024 + (int)threadIdx.x * 4;
    int c[4];
    int s = 0;
#pragma unroll
    for (int t = 0; t < 4; ++t) {
        int i = base + t;
        c[t] = (i < n) ? cnt[i] : 0;
        s += c[t];
    }
    int lane = threadIdx.x & 63, wid = threadIdx.x >> 6;
    int si = s;
    for (int off = 1; off < 64; off <<= 1) {
        int vv = __shfl_up(si, off);
        if (lane >= off) si += vv;
    }
    __shared__ int wg[4];
    if (lane == 63) wg[wid] = si;
    __syncthreads();
    int woff = 0;
    for (int w = 0; w < wid; ++w) woff += wg[w];
    int excl = part[blockIdx.x] + (si - s) + woff;
#pragma unroll
    for (int t = 0; t < 4; ++t) {
        int i = base + t;
        if (i < n) {
            rowstart[i] = excl;
            cursor[i] = excl;
            float dg = (float)c[t] + 2.0f;
            deg[i] = dg;
            dinv[i] = rsqrtf(dg);
        }
        excl += c[t];
    }
}

__global__ void csr_scatter(const int* __restrict__ src, const int* __restrict__ dst,
                            const int* __restrict__ mask, int E,
                            int* __restrict__ cursor, int* __restrict__ csr_src) {
    int e = blockIdx.x * blockDim.x + threadIdx.x;
    if (e >= E) return;
    if (mask && !mask[e]) return;
    int pos = atomicAdd(&cursor[dst[e]], 1);
    csr_src[pos] = src[e];
}

// ---------------- stage-1 aggregation: 8-deep pipelined gather (bf16 in/out) ----------------
__global__ void aggregate_xb(const int* __restrict__ rowstart, const int* __restrict__ csr_src,
                             const float* __restrict__ deg, const float* __restrict__ dinv,
                             const ushort* __restrict__ xb, ushort* __restrict__ out, int n) {
    int node = blockIdx.x * (blockDim.x >> 6) + ((int)threadIdx.x >> 6);
    if (node >= n) return;
    int lane = threadIdx.x & 63;
    int beg = rowstart[node], end = rowstart[node + 1];
    float di = dinv[node];
    float4 acc = make_float4(0.f, 0.f, 0.f, 0.f);
    int j = beg;
    for (; j + 8 <= end; j += 8) {
        int s[8];
#pragma unroll
        for (int u = 0; u < 8; ++u) s[u] = csr_src[j + u];
        float c[8];
#pragma unroll
        for (int u = 0; u < 8; ++u) c[u] = dinv[s[u]] * di;
        ushort4 t[8];
#pragma unroll
        for (int u = 0; u < 8; ++u)
            t[u] = reinterpret_cast<const ushort4*>(&xb[(size_t)s[u] * CIN])[lane];
#pragma unroll
        for (int u = 0; u < 8; ++u) {
            acc.x += c[u] * bf2f(t[u].x);
            acc.y += c[u] * bf2f(t[u].y);
            acc.z += c[u] * bf2f(t[u].z);
            acc.w += c[u] * bf2f(t[u].w);
        }
    }
    for (; j < end; ++j) {
        int s = csr_src[j];
        float coef = dinv[s] * di;
        ushort4 t = reinterpret_cast<const ushort4*>(&xb[(size_t)s * CIN])[lane];
        acc.x += coef * bf2f(t.x);
        acc.y += coef * bf2f(t.y);
        acc.z += coef * bf2f(t.z);
        acc.w += coef * bf2f(t.w);
    }
    float self = 2.0f / deg[node];
    ushort4 t = reinterpret_cast<const ushort4*>(&xb[(size_t)node * CIN])[lane];
    acc.x += self * bf2f(t.x);
    acc.y += self * bf2f(t.y);
    acc.z += self * bf2f(t.z);
    acc.w += self * bf2f(t.w);
    ushort4 o;
    o.x = f2bf(acc.x); o.y = f2bf(acc.y); o.z = f2bf(acc.z); o.w = f2bf(acc.w);
    reinterpret_cast<ushort4*>(&out[(size_t)node * CIN])[lane] = o;
}

// ---------------- stage-2 aggregation: 8-deep gather, f32 out + bias + self + fused stats ----------------
__global__ void aggregate_csr_bf(const int* __restrict__ rowstart, const int* __restrict__ csr_src,
                                 const float* __restrict__ deg, const float* __restrict__ dinv,
                                 const ushort* __restrict__ xWb, const float* __restrict__ b,
                                 float* __restrict__ out, float* __restrict__ Sp, int n) {
    int node = blockIdx.x * (blockDim.x >> 6) + ((int)threadIdx.x >> 6);
    bool valid = node < n;
    int lane = threadIdx.x & 63;
    float ls = 0.f, lq = 0.f;
    if (valid) {
        int beg = rowstart[node], end = rowstart[node + 1];
        float di = dinv[node];
        float4 acc = make_float4(0.f, 0.f, 0.f, 0.f);
        int j = beg;
        for (; j + 8 <= end; j += 8) {
            int s[8];
#pragma unroll
            for (int u = 0; u < 8; ++u) s[u] = csr_src[j + u];
            float c[8];
#pragma unroll
            for (int u = 0; u < 8; ++u) c[u] = dinv[s[u]] * di;
            ushort4 t[8];
#pragma unroll
            for (int u = 0; u < 8; ++u)
                t[u] = reinterpret_cast<const ushort4*>(&xWb[(size_t)s[u] * C2])[lane];
#pragma unroll
            for (int u = 0; u < 8; ++u) {
                acc.x += c[u] * bf2f(t[u].x);
                acc.y += c[u] * bf2f(t[u].y);
                acc.z += c[u] * bf2f(t[u].z);
                acc.w += c[u] * bf2f(t[u].w);
            }
        }
        for (; j < end; ++j) {
            int s = csr_src[j];
            float coef = dinv[s] * di;
            ushort4 t = reinterpret_cast<const ushort4*>(&xWb[(size_t)s * C2])[lane];
            acc.x += coef * bf2f(t.x);
            acc.y += coef * bf2f(t.y);
            acc.z += coef * bf2f(t.z);
            acc.w += coef * bf2f(t.w);
        }
        float self = 2.0f / deg[node];
        ushort4 t = reinterpret_cast<const ushort4*>(&xWb[(size_t)node * C2])[lane];
        float4 bb = reinterpret_cast<const float4*>(b)[lane];
        float4 o;
        o.x = acc.x + self * bf2f(t.x) + bb.x;
        o.y = acc.y + self * bf2f(t.y) + bb.y;
        o.z = acc.z + self * bf2f(t.z) + bb.z;
        o.w = acc.w + self * bf2f(t.w) + bb.w;
        reinterpret_cast<float4*>(&out[(size_t)node * C2])[lane] = o;
        ls = o.x + o.y + o.z + o.w;
        lq = o.x * o.x + o.y * o.y + o.z * o.z + o.w * o.w;
    }
    __shared__ float rs[256], rq[256];
    rs[threadIdx.x] = ls; rq[threadIdx.x] = lq;
    __syncthreads();
    for (int off = 128; off > 0; off >>= 1) {
        if ((int)threadIdx.x < off) {
            rs[threadIdx.x] += rs[threadIdx.x + off];
            rq[threadIdx.x] += rq[threadIdx.x + off];
        }
        __syncthreads();
    }
    if (threadIdx.x == 0) {
        Sp[2 * blockIdx.x] = rs[0];
        Sp[2 * blockIdx.x + 1] = rq[0];
    }
}

// ---------------- final stats fold ----------------
__global__ void reduce_final(const float* __restrict__ Sp, int nb, float* __restrict__ S) {
    float s = 0.f, q = 0.f;
    for (int i = threadIdx.x; i < nb; i += 256) {
        s += Sp[2 * i];
        q += Sp[2 * i + 1];
    }
    __shared__ float ls[256], lq[256];
    ls[threadIdx.x] = s; lq[threadIdx.x] = q;
    __syncthreads();
    for (int off = 128; off > 0; off >>= 1) {
        if ((int)threadIdx.x < off) {
            ls[threadIdx.x] += ls[threadIdx.x + off];
            lq[threadIdx.x] += lq[threadIdx.x + off];
        }
        __syncthreads();
    }
    if (threadIdx.x == 0) { S[0] = ls[0]; S[1] = lq[0]; }
}

// ---------------- norm+relu scores (READ-ONLY h; norm re-applied by consumers) ----------------
template <int C>
__global__ void norm_scores(const float* __restrict__ h, int n, const float* __restrict__ S,
                            float inv_cnt, const float* __restrict__ lnw,
                            const float* __restrict__ lnb, const float* __restrict__ wrel,
                            const float* __restrict__ brel, const float* __restrict__ wroot,
                            float* __restrict__ r, float* __restrict__ score) {
    int node = blockIdx.x * (blockDim.x >> 6) + ((int)threadIdx.x >> 6);
    if (node >= n) return;
    int lane = threadIdx.x & 63;
    float mean = S[0] * inv_cnt;
    float var = S[1] * inv_cnt - mean * mean;
    float istd = 1.f / (sqrtf(fmaxf(var, 0.f)) + EPSV);
    const float4* row = reinterpret_cast<const float4*>(&h[(size_t)node * C]);
    float sr = 0.f, st = 0.f;
#pragma unroll
    for (int kk = 0; kk < C / 256; ++kk) {
        int idx = lane + 64 * kk;
        float4 v = row[idx];
        float4 w = reinterpret_cast<const float4*>(lnw)[idx];
        float4 bb = reinterpret_cast<const float4*>(lnb)[idx];
        float4 w4 = reinterpret_cast<const float4*>(wrel)[idx];
        float4 o4 = reinterpret_cast<const float4*>(wroot)[idx];
        v.x = fmaxf((v.x - mean) * istd * w.x + bb.x, 0.f);
        v.y = fmaxf((v.y - mean) * istd * w.y + bb.y, 0.f);
        v.z = fmaxf((v.z - mean) * istd * w.z + bb.z, 0.f);
        v.w = fmaxf((v.w - mean) * istd * w.w + bb.w, 0.f);
        sr += v.x * w4.x + v.y * w4.y + v.z * w4.z + v.w * w4.w;
        st += v.x * o4.x + v.y * o4.y + v.z * o4.z + v.w * o4.w;
    }
    for (int off = 32; off > 0; off >>= 1) {
        sr += __shfl_down(sr, off);
        st += __shfl_down(st, off);
    }
    if (lane == 0) {
        r[node] = sr;
        score[node] = st + brel[0];
    }
}

// ---------------- gather score over CSR + keyify ----------------
__global__ void gather_score_key(const int* __restrict__ rowstart, const int* __restrict__ csr_src,
                                 const float* __restrict__ r, float* __restrict__ score,
                                 unsigned* __restrict__ key, int n) {
    int i = blockIdx.x * blockDim.x + threadIdx.x;
    if (i >= n) return;
    float s = score[i];
    int beg = rowstart[i], end = rowstart[i + 1];
    int j = beg;
    for (; j + 4 <= end; j += 4) {
        int s0 = csr_src[j], s1 = csr_src[j + 1], s2 = csr_src[j + 2], s3 = csr_src[j + 3];
        s += r[s0] + r[s1] + r[s2] + r[s3];
    }
    for (; j < end; ++j) s += r[csr_src[j]];
    score[i] = s;
    unsigned u = __float_as_uint(s);
    key[i] = (u & 0x80000000u) ? ~u : (u | 0x80000000u);
}

// ---------------- register-resident 4x8-bit radix threshold select (coalesced loads) --------
__global__ void select_thresh_reg(const unsigned* __restrict__ key, int n, unsigned k,
                                  unsigned* __restrict__ sel) {
    __shared__ unsigned hist[256];
    __shared__ unsigned wsum[16];
    __shared__ unsigned s_pref, s_rem;
    int t = threadIdx.x;
    int lane = t & 63, w = t >> 6;

    unsigned kv[20];
#pragma unroll
    for (int i = 0; i < 20; ++i) {
        int idx = t + 1024 * i;
        kv[i] = (idx < n) ? key[idx] : 0u;
    }

    if (t < 256) hist[t] = 0u;
    if (t == 0) { s_pref = 0u; s_rem = k; }
    __syncthreads();

    unsigned pref = 0u, msk = 0u, rem = k;
#pragma unroll
    for (int pass = 0; pass < 4; ++pass) {
        int shift = 24 - 8 * pass;
#pragma unroll
        for (int i = 0; i < 20; ++i) {
            int idx = t + 1024 * i;
            if (idx < n && (kv[i] & msk) == pref)
                atomicAdd(&hist[(kv[i] >> shift) & 255u], 1u);
        }
        __syncthreads();
        unsigned val = (t < 256) ? hist[255 - t] : 0u;  // descending
        unsigned si = val;
#pragma unroll
        for (int off = 1; off < 64; off <<= 1) {
            unsigned vv = __shfl_up(si, off);
            if (lane >= off) si += vv;
        }
        if (lane == 63 && w < 4) wsum[w] = si;
        __syncthreads();
        if (t < 256) hist[t] = 0u;
        if (t < 256) {
            unsigned wpre = 0u;
            for (int i = 0; i < w; ++i) wpre += wsum[i];
            unsigned incl = wpre + si;
            unsigned excl = incl - val;
            if (excl < rem && rem <= incl) {
                s_pref = pref | ((unsigned)(255 - t) << shift);
                s_rem = rem - excl;
            }
        }
        __syncthreads();
        pref = s_pref;
        rem = s_rem;
        msk = 0xFFFFFFFFu << shift;
    }
    if (t == 0) { sel[0] = pref; sel[1] = rem; }
}

// ---------------- multi-block deterministic select + compact ----------------
__global__ void sc_partial(const unsigned* __restrict__ key, int n, const unsigned* __restrict__ sel,
                           int* __restrict__ gpart, int* __restrict__ epart) {
    unsigned thr = sel[0];
    int base = blockIdx.x * 1024 + (int)threadIdx.x * 4;
    int gs = 0, es = 0;
#pragma unroll
    for (int t = 0; t < 4; ++t) {
        int i = base + t;
        if (i < n) {
            unsigned u = key[i];
            gs += (u > thr); es += (u == thr);
        }
    }
    for (int off = 32; off > 0; off >>= 1) {
        gs += __shfl_down(gs, off);
        es += __shfl_down(es, off);
    }
    __shared__ int sg[4], se[4];
    int wid = threadIdx.x >> 6;
    if ((threadIdx.x & 63) == 0) { sg[wid] = gs; se[wid] = es; }
    __syncthreads();
    if (threadIdx.x == 0) {
        gpart[blockIdx.x] = sg[0] + sg[1] + sg[2] + sg[3];
        epart[blockIdx.x] = se[0] + se[1] + se[2] + se[3];
    }
}

// reads RAW per-block totals; each block sums its prefix inline (nb <= 20)
__global__ void sc_final(const unsigned* __restrict__ key, int n, const unsigned* __restrict__ sel,
                         const int* __restrict__ gpart, const int* __restrict__ epart,
                         int* __restrict__ kept, int* __restrict__ inv) {
    unsigned thr = sel[0];
    int tie = (int)sel[1];
    int gp0 = 0, ep0 = 0;
    for (int b = 0; b < (int)blockIdx.x; ++b) { gp0 += gpart[b]; ep0 += epart[b]; }
    int base = blockIdx.x * 1024 + (int)threadIdx.x * 4;
    int gl[4], el[4];
    int gs = 0, es = 0;
#pragma unroll
    for (int t = 0; t < 4; ++t) {
        int i = base + t;
        gl[t] = 0; el[t] = 0;
        if (i < n) {
            unsigned u = key[i];
            gl[t] = (u > thr); el[t] = (u == thr);
        }
        gs += gl[t]; es += el[t];
    }
    int lane = threadIdx.x & 63, wid = threadIdx.x >> 6;
    int gi = gs, ei = es;
    for (int off = 1; off < 64; off <<= 1) {
        int gg = __shfl_up(gi, off), ee = __shfl_up(ei, off);
        if (lane >= off) { gi += gg; ei += ee; }
    }
    __shared__ int wg[4], we[4];
    if (lane == 63) { wg[wid] = gi; we[wid] = ei; }
    __syncthreads();
    int wgo = 0, weo = 0;
    for (int w = 0; w < wid; ++w) { wgo += wg[w]; weo += we[w]; }
    int gp = gp0 + (gi - gs) + wgo;
    int ep = ep0 + (ei - es) + weo;
#pragma unroll
    for (int t = 0; t < 4; ++t) {
        int i = base + t;
        if (i < n) {
            int keep = gl[t] | (el[t] & ((ep < tie) ? 1 : 0));
            kept[i] = keep;
            inv[i] = gp + ((ep < tie) ? ep : tie);
        }
        gp += gl[t]; ep += el[t];
    }
}

// ---------------- pool apply: wave per node, applies norm+relu on the fly, bf16 out (C=512) ----------------
__global__ void pool_apply_rows(const float* __restrict__ h, const float* __restrict__ score,
                                const int* __restrict__ kept, const int* __restrict__ inv,
                                int n, const float* __restrict__ S, float inv_cnt,
                                const float* __restrict__ lnw, const float* __restrict__ lnb,
                                ushort* __restrict__ hp) {
    int node = blockIdx.x * (blockDim.x >> 6) + ((int)threadIdx.x >> 6);
    if (node >= n) return;
    if (!kept[node]) return;
    int lane = threadIdx.x & 63;
    float mean = S[0] * inv_cnt;
    float var = S[1] * inv_cnt - mean * mean;
    float istd = 1.f / (sqrtf(fmaxf(var, 0.f)) + EPSV);
    float tw = tanhf(score[node]);
    const float4* src = reinterpret_cast<const float4*>(&h[(size_t)node * C1]);
    ushort4* dst = reinterpret_cast<ushort4*>(&hp[(size_t)inv[node] * C1]);
#pragma unroll
    for (int v = 0; v < 2; ++v) {
        int idx = lane + 64 * v;
        float4 a = src[idx];
        float4 w = reinterpret_cast<const float4*>(lnw)[idx];
        float4 bb = reinterpret_cast<const float4*>(lnb)[idx];
        ushort4 o;
        o.x = f2bf(fmaxf((a.x - mean) * istd * w.x + bb.x, 0.f) * tw);
        o.y = f2bf(fmaxf((a.y - mean) * istd * w.y + bb.y, 0.f) * tw);
        o.z = f2bf(fmaxf((a.z - mean) * istd * w.z + bb.z, 0.f) * tw);
        o.w = f2bf(fmaxf((a.w - mean) * istd * w.w + bb.w, 0.f) * tw);
        dst[idx] = o;
    }
}

// ---------------- edge relabel (+ zero next stage's count buffer) ----------------
__global__ void edge_relabel(const int* __restrict__ src, const int* __restrict__ dst, int E,
                             const int* __restrict__ kept, const int* __restrict__ inv,
                             int* __restrict__ src2, int* __restrict__ dst2,
                             int* __restrict__ mask2, int* __restrict__ zbuf, int nz) {
    int e = blockIdx.x * blockDim.x + threadIdx.x;
    if (e < nz) zbuf[e] = 0;
    if (e >= E) return;
    int s = src[e], d = dst[e];
    int m = kept[s] & kept[d];
    mask2[e] = m;
    src2[e] = m ? inv[s] : 0;
    dst2[e] = m ? inv[d] : 0;
}

// ---------------- masked weighted column mean (norm+relu applied on the fly) ----------------
__global__ void colmean_part(const float* __restrict__ h, const float* __restrict__ score,
                             const int* __restrict__ kept, int n, const float* __restrict__ S,
                             float inv_cnt, const float* __restrict__ lnw,
                             const float* __restrict__ lnb, float* __restrict__ Gp) {
    __shared__ float w[CM_ROWS];
    int i0 = blockIdx.x * CM_ROWS;
    int t = threadIdx.x;
    float mean = S[0] * inv_cnt;
    float var = S[1] * inv_cnt - mean * mean;
    float istd = 1.f / (sqrtf(fmaxf(var, 0.f)) + EPSV);
    float wn = lnw[t] * istd;
    float bn = lnb[t] - mean * wn;
    for (int i = t; i < CM_ROWS; i += 256) {
        int idx = i0 + i;
        w[i] = (idx < n && kept[idx]) ? tanhf(score[idx]) : 0.f;
    }
    __syncthreads();
    float acc = 0.f;
    int rows = min(CM_ROWS, n - i0);
#pragma unroll 8
    for (int ri = 0; ri < rows; ++ri)
        acc = fmaf(w[ri], fmaxf(fmaf(h[(size_t)(i0 + ri) * C2 + t], wn, bn), 0.f), acc);
    Gp[blockIdx.x * 256 + t] = acc;
}

// ---------------- fused: fold colmean partials + final GEMV ----------------
__global__ void final_fused(const float* __restrict__ Gp, int nb, float invk,
                            const float* __restrict__ Wf, const float* __restrict__ bf,
                            float* __restrict__ out) {
    __shared__ float g[256];
    int t = threadIdx.x;  // 256
    float s = 0.f;
    for (int b = 0; b < nb; ++b) s += Gp[b * 256 + t];
    g[t] = s * invk;
    __syncthreads();
    if (t < NOUT) {
        float acc = bf[t];
        for (int c = 0; c < 256; ++c) acc = fmaf(g[c], Wf[c * NOUT + t], acc);
        out[t] = acc;
    }
}

// =======================================================================================
extern "C" void kernel_launch(void* const* d_in, const int* in_sizes, int n_in,
                              void* d_out, int out_size, void* d_ws, size_t ws_size,
                              hipStream_t stream) {
    const float* x      = (const float*)d_in[0];
    const int*   ei     = (const int*)d_in[1];
    const float* W1     = (const float*)d_in[2];
    const float* b1     = (const float*)d_in[3];
    const float* ln1w   = (const float*)d_in[4];
    const float* ln1b   = (const float*)d_in[5];
    const float* p1wrel = (const float*)d_in[6];
    const float* p1brel = (const float*)d_in[7];
    const float* p1wroot= (const float*)d_in[8];
    const float* W2     = (const float*)d_in[9];
    const float* b2     = (const float*)d_in[10];
    const float* ln2w   = (const float*)d_in[11];
    const float* ln2b   = (const float*)d_in[12];
    const float* p2wrel = (const float*)d_in[13];
    const float* p2brel = (const float*)d_in[14];
    const float* p2wroot= (const float*)d_in[15];
    const float* Wf     = (const float*)d_in[16];
    const float* bf     = (const float*)d_in[17];
    float* out = (float*)d_out;
    char* ws = (char*)d_ws;

    const int* src1 = ei;
    const int* dst1 = ei + NE;

    // ---- workspace layout (bytes) ----
    const size_t o0     = 0;          // 40.96 MB: h1 f32; later h2 f32 @+0, xW2b bf16 @+10,240,000
    const size_t o1     = 40960000;   // 10.24 MB: aggb bf16; later h1pb bf16
    const size_t oXb    = 51200000;   // 10,240,000 : xb bf16
    const size_t oW1t   = 61440000;
    const size_t oW2t   = 61702144;
    const size_t oSrc2  = 61964288;
    const size_t oDst2  = 63244288;
    const size_t oMask2 = 64524288;
    const size_t oCsr   = 65804288;
    const size_t oRow   = 67084288;
    const size_t oCur   = 67164352;
    const size_t oDeg   = 67244352;
    const size_t oDinv  = 67324352;
    const size_t oR     = 67404352;
    const size_t oScore1= 67484352;
    const size_t oKeyu  = 67564352;
    const size_t oKept  = 67644352;
    const size_t oInv   = 67724352;
    const size_t oScore2= 67804352;
    const size_t oKeyu2 = 67844352;
    const size_t oKept2 = 67884352;
    const size_t oInv2  = 67924352;
    const size_t oS     = 67964352;
    const size_t oSel   = 67964416;
    const size_t oGpart = 67964480;
    const size_t oEpart = 67964736;
    const size_t oGp    = 68232256;   // 81,920 : colmean partials
    const size_t oSp    = 68314176;   // 32,768 : stats partials

    float*  h1    = (float*)(ws + o0);
    float*  h2    = (float*)(ws + o0);
    ushort* xW2b  = (ushort*)(ws + o0 + 10240000);
    ushort* aggb  = (ushort*)(ws + o1);
    ushort* h1pb  = (ushort*)(ws + o1);
    ushort* xb    = (ushort*)(ws + oXb);
    ushort* W1t   = (ushort*)(ws + oW1t);
    ushort* W2t   = (ushort*)(ws + oW2t);
    int*    src2  = (int*)(ws + oSrc2);
    int*    dst2  = (int*)(ws + oDst2);
    int*    mask2 = (int*)(ws + oMask2);
    int*    csr   = (int*)(ws + oCsr);
    int*    row   = (int*)(ws + oRow);
    int*    cur   = (int*)(ws + oCur);
    float*  deg   = (float*)(ws + oDeg);
    float*  dinv  = (float*)(ws + oDinv);
    float*  r     = (float*)(ws + oR);
    float*  score1= (float*)(ws + oScore1);
    unsigned* keyu  = (unsigned*)(ws + oKeyu);
    int*    kept  = (int*)(ws + oKept);
    int*    inv   = (int*)(ws + oInv);
    float*  score2= (float*)(ws + oScore2);
    unsigned* keyu2 = (unsigned*)(ws + oKeyu2);
    int*    kept2 = (int*)(ws + oKept2);
    int*    inv2  = (int*)(ws + oInv2);
    float*  S     = (float*)(ws + oS);
    unsigned* sel  = (unsigned*)(ws + oSel);
    int*    gpart = (int*)(ws + oGpart);
    int*    epart = (int*)(ws + oEpart);
    float*  Gp    = (float*)(ws + oGp);
    float*  Sp    = (float*)(ws + oSp);

    const int nb1 = cdiv(N1, 1024);     // 20
    const int nb2 = cdiv(K1, 1024);     // 10
    const int nbc = cdiv(K1, CM_ROWS);  // 79
    const int g1x = cdiv(N1, 128), g1y = C1 / 128;   // stat blocks (628)
    const int agg2b = cdiv(K1, 4);      // 2500 stat blocks
    const float ic1 = 1.f / ((float)N1 * C1);
    const float ic2 = 1.f / ((float)K1 * C2);

    // ================= Stage 1 =================
    f32_to_bf16<<<cdiv(N1 * CIN / 4, 256), 256, 0, stream>>>(x, xb, N1 * CIN / 4, cur, N1);
    count_deg<<<cdiv(NE, 256), 256, 0, stream>>>(dst1, nullptr, NE, cur);
    dp_partial<<<nb1, 256, 0, stream>>>(cur, N1, gpart);
    scan64k<<<1, 64, 0, stream>>>(nb1, gpart, row + N1);
    dp_final<<<nb1, 256, 0, stream>>>(cur, N1, gpart, row, cur, deg, dinv);
    csr_scatter<<<cdiv(NE, 256), 256, 0, stream>>>(src1, dst1, nullptr, NE, cur, csr);

    aggregate_xb<<<cdiv(N1, 4), 256, 0, stream>>>(row, csr, deg, dinv, xb, aggb, N1);

    conv_transpose_bf16<<<cdiv(CIN * C1, 256), 256, 0, stream>>>(W1, W1t, CIN, C1);
    gemm_bf16_mfma<false, true><<<dim3(g1x, g1y), 256, 0, stream>>>(
        aggb, W1t, b1, h1, nullptr, Sp, N1, C1, CIN);
    reduce_final<<<1, 256, 0, stream>>>(Sp, g1x * g1y, S);

    norm_scores<C1><<<cdiv(N1, 4), 256, 0, stream>>>(h1, N1, S, ic1,
                                                     ln1w, ln1b, p1wrel, p1brel, p1wroot, r, score1);
    gather_score_key<<<cdiv(N1, 256), 256, 0, stream>>>(row, csr, r, score1, keyu, N1);

    select_thresh_reg<<<1, 1024, 0, stream>>>(keyu, N1, K1, sel);
    sc_partial<<<nb1, 256, 0, stream>>>(keyu, N1, sel, gpart, epart);
    sc_final<<<nb1, 256, 0, stream>>>(keyu, N1, sel, gpart, epart, kept, inv);

    pool_apply_rows<<<cdiv(N1, 4), 256, 0, stream>>>(h1, score1, kept, inv, N1, S,
                                                     ic1, ln1w, ln1b, h1pb);
    edge_relabel<<<cdiv(NE, 256), 256, 0, stream>>>(src1, dst1, NE, kept, inv,
                                                    src2, dst2, mask2, cur, K1);

    // ================= Stage 2 =================
    conv_transpose_bf16<<<cdiv(C1 * C2, 256), 256, 0, stream>>>(W2, W2t, C1, C2);
    gemm_bf16_mfma<true, false><<<dim3(cdiv(K1, 128), C2 / 128), 256, 0, stream>>>(
        h1pb, W2t, nullptr, nullptr, xW2b, nullptr, K1, C2, C1);

    count_deg<<<cdiv(NE, 256), 256, 0, stream>>>(dst2, mask2, NE, cur);
    dp_partial<<<nb2, 256, 0, stream>>>(cur, K1, gpart);
    scan64k<<<1, 64, 0, stream>>>(nb2, gpart, row + K1);
    dp_final<<<nb2, 256, 0, stream>>>(cur, K1, gpart, row, cur, deg, dinv);
    csr_scatter<<<cdiv(NE, 256), 256, 0, stream>>>(src2, dst2, mask2, NE, cur, csr);

    aggregate_csr_bf<<<agg2b, 256, 0, stream>>>(row, csr, deg, dinv, xW2b, b2, h2, Sp, K1);
    reduce_final<<<1, 256, 0, stream>>>(Sp, agg2b, S);

    norm_scores<C2><<<cdiv(K1, 4), 256, 0, stream>>>(h2, K1, S, ic2,
                                                     ln2w, ln2b, p2wrel, p2brel, p2wroot, r, score2);
    gather_score_key<<<cdiv(K1, 256), 256, 0, stream>>>(row, csr, r, score2, keyu2, K1);

    select_thresh_reg<<<1, 1024, 0, stream>>>(keyu2, K1, K2, sel);
    sc_partial<<<nb2, 256, 0, stream>>>(keyu2, K1, sel, gpart, epart);
    sc_final<<<nb2, 256, 0, stream>>>(keyu2, K1, sel, gpart, epart, kept2, inv2);

    // ================= readout =================
    colmean_part<<<nbc, 256, 0, stream>>>(h2, score2, kept2, K1, S, ic2,
                                          ln2w, ln2b, Gp);
    final_fused<<<1, 256, 0, stream>>>(Gp, nbc, 1.f / (float)K2, Wf, bf, out);
}